// Round 1
// baseline (104.408 us; speedup 1.0000x reference)
//
#include <hip/hip_runtime.h>

// LIF spiking-neuron forward (inference path of the reference's scan).
// x: [B=32, C=128, T=16, H=32, W=32] fp32, out: same shape fp32 (0/1 spikes).
// Recurrence per (b,c,h,w) over T; memory layout puts T at stride H*W=1024,
// so each thread owns 4 contiguous spatial elements and walks t with
// coalesced float4 accesses (16 B/lane).

constexpr float K_THRESH = 0.5f;
constexpr float K_BETA   = 0.75f;
constexpr int   K_T      = 16;
constexpr int   K_HW     = 32 * 32;   // 1024

__global__ __launch_bounds__(256)
void lif_fwd_kernel(const float* __restrict__ x, float* __restrict__ out) {
    // tid in [0, B*C*HW/4) ; 256 threads cover one (b,c)'s HW/4=256 float4s.
    const int tid = blockIdx.x * blockDim.x + threadIdx.x;
    const int bc  = tid >> 8;            // / 256
    const int s4  = (tid & 255) << 2;    // * 4 : starting spatial element
    const size_t base = (size_t)bc * (K_T * K_HW) + (size_t)s4;

    float m0 = 0.0f, m1 = 0.0f, m2 = 0.0f, m3 = 0.0f;

#pragma unroll
    for (int t = 0; t < K_T; ++t) {
        const size_t off = base + (size_t)t * K_HW;
        const float4 xi = *reinterpret_cast<const float4*>(x + off);
        float4 s;

        // Separate mul/add (no FMA contraction) to stay bit-identical to the
        // reference's mem*beta + x. Reset subtracts exactly 0.5 (exact fp32).
        m0 = __fadd_rn(__fmul_rn(m0, K_BETA), xi.x);
        s.x = (m0 > K_THRESH) ? 1.0f : 0.0f;
        m0 = __fsub_rn(m0, __fmul_rn(s.x, K_THRESH));

        m1 = __fadd_rn(__fmul_rn(m1, K_BETA), xi.y);
        s.y = (m1 > K_THRESH) ? 1.0f : 0.0f;
        m1 = __fsub_rn(m1, __fmul_rn(s.y, K_THRESH));

        m2 = __fadd_rn(__fmul_rn(m2, K_BETA), xi.z);
        s.z = (m2 > K_THRESH) ? 1.0f : 0.0f;
        m2 = __fsub_rn(m2, __fmul_rn(s.z, K_THRESH));

        m3 = __fadd_rn(__fmul_rn(m3, K_BETA), xi.w);
        s.w = (m3 > K_THRESH) ? 1.0f : 0.0f;
        m3 = __fsub_rn(m3, __fmul_rn(s.w, K_THRESH));

        *reinterpret_cast<float4*>(out + off) = s;
    }
}

extern "C" void kernel_launch(void* const* d_in, const int* in_sizes, int n_in,
                              void* d_out, int out_size, void* d_ws, size_t ws_size,
                              hipStream_t stream) {
    const float* x   = (const float*)d_in[0];
    float*       out = (float*)d_out;

    const int total   = in_sizes[0];            // 67,108,864 elements
    const int threads = total / (K_T * 4);      // 1,048,576 threads
    const int block   = 256;
    const int grid    = threads / block;        // 4096 blocks

    lif_fwd_kernel<<<grid, block, 0, stream>>>(x, out);
}

// Round 3
// 92.053 us; speedup vs baseline: 1.1342x; 1.1342x over previous
//
#include <hip/hip_runtime.h>

// LIF spiking-neuron forward. x: [B=32,C=128,T=16,H=32,W=32] fp32 -> spikes.
// One thread owns 4 contiguous spatial elements of one (b,c) and walks t
// (stride HW=1024 floats). Phase-split: issue all 16 independent 16B loads
// first (16 outstanding VMEM ops/wave), then the sequential recurrence +
// nontemporal stores. Both streams are touch-once -> nontemporal (nt) to
// reduce L2/LLC write-allocate pressure.
//
// NOTE: __builtin_nontemporal_* requires a clang native vector type, not
// HIP_vector_type<float,4> -> use ext_vector_type(4).

typedef float vfloat4 __attribute__((ext_vector_type(4)));

constexpr float K_THRESH = 0.5f;
constexpr float K_BETA   = 0.75f;
constexpr int   K_T      = 16;
constexpr int   K_HW     = 32 * 32;   // 1024

__global__ __launch_bounds__(256)
void lif_fwd_kernel(const float* __restrict__ x, float* __restrict__ out) {
    const int tid = blockIdx.x * blockDim.x + threadIdx.x;
    const int bc  = tid >> 8;            // / 256 : which (b,c) plane
    const int s4  = (tid & 255) << 2;    // * 4   : starting spatial element
    const size_t base = (size_t)bc * (K_T * K_HW) + (size_t)s4;

    // Phase 1: all 16 loads in flight (independent addresses, full unroll ->
    // xi[] stays in registers; compiler emits counted vmcnt waits per use).
    vfloat4 xi[K_T];
#pragma unroll
    for (int t = 0; t < K_T; ++t) {
        xi[t] = __builtin_nontemporal_load(
            reinterpret_cast<const vfloat4*>(x + base + (size_t)t * K_HW));
    }

    // Phase 2: sequential LIF recurrence, store each t-slice as computed.
    float m0 = 0.0f, m1 = 0.0f, m2 = 0.0f, m3 = 0.0f;
#pragma unroll
    for (int t = 0; t < K_T; ++t) {
        vfloat4 s;

        // Separate mul/add (no FMA contraction) -> bit-identical to the
        // reference's mem*beta + x. Reset subtracts exactly 0.5.
        m0 = __fadd_rn(__fmul_rn(m0, K_BETA), xi[t].x);
        s.x = (m0 > K_THRESH) ? 1.0f : 0.0f;
        m0 = __fsub_rn(m0, __fmul_rn(s.x, K_THRESH));

        m1 = __fadd_rn(__fmul_rn(m1, K_BETA), xi[t].y);
        s.y = (m1 > K_THRESH) ? 1.0f : 0.0f;
        m1 = __fsub_rn(m1, __fmul_rn(s.y, K_THRESH));

        m2 = __fadd_rn(__fmul_rn(m2, K_BETA), xi[t].z);
        s.z = (m2 > K_THRESH) ? 1.0f : 0.0f;
        m2 = __fsub_rn(m2, __fmul_rn(s.z, K_THRESH));

        m3 = __fadd_rn(__fmul_rn(m3, K_BETA), xi[t].w);
        s.w = (m3 > K_THRESH) ? 1.0f : 0.0f;
        m3 = __fsub_rn(m3, __fmul_rn(s.w, K_THRESH));

        __builtin_nontemporal_store(
            s, reinterpret_cast<vfloat4*>(out + base + (size_t)t * K_HW));
    }
}

extern "C" void kernel_launch(void* const* d_in, const int* in_sizes, int n_in,
                              void* d_out, int out_size, void* d_ws, size_t ws_size,
                              hipStream_t stream) {
    const float* x   = (const float*)d_in[0];
    float*       out = (float*)d_out;

    const int total   = in_sizes[0];            // 67,108,864 elements
    const int threads = total / (K_T * 4);      // 1,048,576 threads
    const int block   = 256;
    const int grid    = threads / block;        // 4096 blocks

    lif_fwd_kernel<<<grid, block, 0, stream>>>(x, out);
}